// Round 14
// baseline (117.758 us; speedup 1.0000x reference)
//
#include <hip/hip_runtime.h>

#define B_SZ  2
#define N_PTS 16384
#define M_CTR 4096
#define C_FT  32
#define K_NB  32
#define NCH   35   // 3 + C_FT
#define CH_STRIDE (K_NB * M_CTR)   // 131072
#define CELLS 10
#define NCELL (CELLS * CELLS * CELLS)
#define CAP   64                   // slots per cell; P(count>64|lam=16.4)~1e-18

// ---------------------------------------------------------------------------
// Exact single-rounded f32 ops, opaque to the compiler. v_fma_f32 ONLY where
// the numpy golden fuses (einsum cp accumulation). absmax==0.0 since R6 —
// DO NOT change the math.
// ---------------------------------------------------------------------------
__device__ __forceinline__ float fmul(float a, float b) {
    float r; asm("v_mul_f32 %0, %1, %2" : "=v"(r) : "v"(a), "v"(b)); return r;
}
__device__ __forceinline__ float fadd(float a, float b) {
    float r; asm("v_add_f32 %0, %1, %2" : "=v"(r) : "v"(a), "v"(b)); return r;
}
__device__ __forceinline__ float fsub(float a, float b) {
    float r; asm("v_sub_f32 %0, %1, %2" : "=v"(r) : "v"(a), "v"(b)); return r;
}
__device__ __forceinline__ float ffma(float a, float b, float c) {
    float r; asm("v_fma_f32 %0, %1, %2, %3" : "=v"(r) : "v"(a), "v"(b), "v"(c));
    return r;
}

__device__ __forceinline__ bool bq_valid(float x, float y, float z,
                                         float cx, float cy, float cz,
                                         float c2, float r2) {
    const float p2 = fadd(fadd(fmul(x, x), fmul(y, y)), fmul(z, z));
    const float cp = ffma(cz, z, ffma(cy, y, fmul(cx, x)));
    return fsub(fadd(c2, p2), fmul(2.0f, cp)) < r2;
}

__device__ __forceinline__ int cell_of(float x, float y, float z) {
    int ci = (int)(x * 10.0f); ci = ci < 0 ? 0 : (ci > 9 ? 9 : ci);
    int cj = (int)(y * 10.0f); cj = cj < 0 ? 0 : (cj > 9 ? 9 : cj);
    int ck = (int)(z * 10.0f); ck = ck < 0 ? 0 : (ck > 9 ? 9 : ck);
    return (ck * CELLS + cj) * CELLS + ci;   // x fastest
}

// ---------------------------------------------------------------------------
// Build, ONE dispatch @1024 threads (replaces hist+scan+scatter+transpose):
//   blocks 0..1   : per-batch fixed-capacity cell append. LDS cursors
//                   (zeroed in-block -> no global memset node), LDS atomicAdd
//                   for slot, direct 16B write to cells[cell][slot]. Counts
//                   dumped to cellcnt at the end. No scan needed.
//   blocks 2..513 : transpose points+feats -> pf (B,N,36), n order.
// Slot order within a cell is arbitrary — bq's n-bitmap restores exact
// reference ordering.
// ---------------------------------------------------------------------------
__global__ __launch_bounds__(1024) void build_kernel(
    const float* __restrict__ points,   // (B,3,N)
    const float* __restrict__ feats,    // (B,C,N)
    float4* __restrict__ cells,         // (B,NCELL,CAP) {x,y,z,n}
    int* __restrict__ cellcnt,          // (B,NCELL)
    float* __restrict__ pf)             // (B,N,36)
{
    if (blockIdx.x < B_SZ) {
        const int b = blockIdx.x;
        const int t = threadIdx.x;
        __shared__ int cur[NCELL];
        if (t < NCELL) cur[t] = 0;
        __syncthreads();

        const float* __restrict__ px = points + (b * 3 + 0) * N_PTS;
        const float* __restrict__ py = points + (b * 3 + 1) * N_PTS;
        const float* __restrict__ pz = points + (b * 3 + 2) * N_PTS;
        float4* __restrict__ cb = cells + (size_t)b * NCELL * CAP;
#pragma unroll
        for (int i = 0; i < 16; ++i) {
            const int n = t + i * 1024;
            const float x = px[n], y = py[n], z = pz[n];
            const int c = cell_of(x, y, z);
            const int pos = atomicAdd(&cur[c], 1);
            if (pos < CAP)
                cb[c * CAP + pos] = make_float4(x, y, z, __int_as_float(n));
        }
        __syncthreads();
        if (t < NCELL) cellcnt[b * NCELL + t] = cur[t];
    } else {
        __shared__ float tile[64][37];
        const int bid = blockIdx.x - B_SZ;
        const int t  = threadIdx.x;
        const int b  = bid >> 8;
        const int n0 = (bid & 255) * 64;
        for (int i = t; i < NCH * 64; i += 1024) {
            const int r = i >> 6;
            const int c = i & 63;
            float v;
            if (r < 3) v = points[(b * 3 + r) * N_PTS + n0 + c];
            else       v = feats[(b * C_FT + (r - 3)) * N_PTS + n0 + c];
            tile[c][r] = v;
        }
        if (t < 64) tile[t][35] = 0.0f;
        __syncthreads();
        float* __restrict__ dst = pf + ((size_t)b * N_PTS + n0) * 36;
        for (int o = t; o < 64 * 36; o += 1024) {
            const int c = o / 36;
            const int r = o - c * 36;
            dst[o] = tile[c][r];
        }
    }
}

// ---------------------------------------------------------------------------
// Ball query on fixed-capacity cell lists. One wave per center; <=27 cells,
// each scanned in ONE wave-pass (count <= 64). Per-wave LDS bitmap over
// original n restores exact index order (sort-all-valid, take first K).
// ---------------------------------------------------------------------------
__global__ __launch_bounds__(256) void ball_query_kernel(
    const float4* __restrict__ cells,    // (B,NCELL,CAP)
    const int* __restrict__ cellcnt,     // (B,NCELL)
    const float* __restrict__ centers,   // (B,3,M)
    int* __restrict__ idx_out)           // (B,K,M)
{
    const int lane = threadIdx.x & 63;
    const int wid  = threadIdx.x >> 6;
    const int cid  = blockIdx.x * 4 + wid;
    const int b = cid >> 12;
    const int m = cid & (M_CTR - 1);

    const float r2 = (float)(0.1 * 0.1);

    const float cx = centers[(b * 3 + 0) * M_CTR + m];
    const float cy = centers[(b * 3 + 1) * M_CTR + m];
    const float cz = centers[(b * 3 + 2) * M_CTR + m];
    const float c2 = fadd(fadd(fmul(cx, cx), fmul(cy, cy)), fmul(cz, cz));

    __shared__ unsigned bitmap[4][N_PTS / 32];   // 2 KB per wave
    unsigned* bm = bitmap[wid];
#pragma unroll
    for (int j = 0; j < 8; ++j) bm[lane * 8 + j] = 0u;

    int ci = (int)(cx * 10.0f); ci = ci < 0 ? 0 : (ci > 9 ? 9 : ci);
    int cj = (int)(cy * 10.0f); cj = cj < 0 ? 0 : (cj > 9 ? 9 : cj);
    int ck = (int)(cz * 10.0f); ck = ck < 0 ? 0 : (ck > 9 ? 9 : ck);
    const int i0 = ci > 0 ? ci - 1 : 0;
    const int i1 = ci < 9 ? ci + 1 : 9;
    const float4* __restrict__ cb = cells + (size_t)b * NCELL * CAP;
    const int* __restrict__ cnts = cellcnt + b * NCELL;

    for (int d = 0; d < 9; ++d) {
        const int jj = cj + (d % 3) - 1;
        const int kk = ck + (d / 3) - 1;
        if (jj < 0 || jj > 9 || kk < 0 || kk > 9) continue;
        const int base = (kk * CELLS + jj) * CELLS;
        for (int ii = i0; ii <= i1; ++ii) {
            const int c = base + ii;
            int cnt = cnts[c];
            cnt = cnt > CAP ? CAP : cnt;
            if (lane < cnt) {
                const float4 p = cb[c * CAP + lane];
                if (bq_valid(p.x, p.y, p.z, cx, cy, cz, c2, r2)) {
                    const int n = __float_as_int(p.w);
                    atomicOr((int*)&bm[n >> 5], 1 << (n & 31));
                }
            }
        }
    }

    unsigned w[8];
    int cnt = 0;
#pragma unroll
    for (int j = 0; j < 8; ++j) { w[j] = bm[lane * 8 + j]; cnt += __popc(w[j]); }

    int incl = cnt;
    for (int off = 1; off < 64; off <<= 1) {
        const int v = __shfl_up(incl, off);
        if (lane >= off) incl += v;
    }
    const int total = __shfl(incl, 63);
    int slot = incl - cnt;

    int firstbit = 0x7fffffff;
#pragma unroll
    for (int j = 0; j < 8; ++j) {
        if (w[j] && firstbit == 0x7fffffff)
            firstbit = lane * 256 + j * 32 + (__ffs(w[j]) - 1);
    }
    for (int off = 32; off > 0; off >>= 1)
        firstbit = min(firstbit, __shfl_xor(firstbit, off));
    const int first_idx = (total == 0) ? 0 : firstbit;

    int* __restrict__ dst = idx_out + (b * K_NB) * M_CTR + m;
#pragma unroll
    for (int j = 0; j < 8; ++j) {
        unsigned x = w[j];
        while (x && slot < K_NB) {
            const int bit = __ffs(x) - 1;
            dst[slot * M_CTR] = lane * 256 + j * 32 + bit;
            x &= x - 1;
            ++slot;
        }
    }
    if (lane >= total && lane < K_NB) dst[lane * M_CTR] = first_idx;
}

// ---------------------------------------------------------------------------
// Gather: R12's proven 2-wide form. 2 consecutive-m elements per thread:
// float2 plane stores (512 B/wave), int2 idx loads, 18-load MLP.
// ---------------------------------------------------------------------------
__global__ __launch_bounds__(256) void gather_kernel(
    const float* __restrict__ pf,       // (B,N,36), n order
    const float* __restrict__ centers,  // (B,3,M)
    const int* __restrict__ idx,        // (B,K,M)
    float* __restrict__ out)            // (B,35,K,M)
{
    const int t = blockIdx.x * 256 + threadIdx.x;   // 0..131071
    const int m = (t & (M_CTR / 2 - 1)) * 2;
    const int k = (t >> 11) & (K_NB - 1);
    const int b = t >> 16;

    const int2 nn = *(const int2*)&idx[(b * K_NB + k) * M_CTR + m];
    const float4* __restrict__ s0 =
        (const float4*)(pf + ((size_t)b * N_PTS + nn.x) * 36);
    const float4* __restrict__ s1 =
        (const float4*)(pf + ((size_t)b * N_PTS + nn.y) * 36);

    float4 f0[9], f1[9];
#pragma unroll
    for (int i = 0; i < 9; ++i) { f0[i] = s0[i]; f1[i] = s1[i]; }

    const float2 cx = *(const float2*)&centers[(b * 3 + 0) * M_CTR + m];
    const float2 cy = *(const float2*)&centers[(b * 3 + 1) * M_CTR + m];
    const float2 cz = *(const float2*)&centers[(b * 3 + 2) * M_CTR + m];

    float v0[36], v1[36];
#pragma unroll
    for (int i = 0; i < 9; ++i) {
        v0[4 * i + 0] = f0[i].x; v0[4 * i + 1] = f0[i].y;
        v0[4 * i + 2] = f0[i].z; v0[4 * i + 3] = f0[i].w;
        v1[4 * i + 0] = f1[i].x; v1[4 * i + 1] = f1[i].y;
        v1[4 * i + 2] = f1[i].z; v1[4 * i + 3] = f1[i].w;
    }
    v0[0] -= cx.x; v0[1] -= cy.x; v0[2] -= cz.x;   // single f32 subtract
    v1[0] -= cx.y; v1[1] -= cy.y; v1[2] -= cz.y;

    float* __restrict__ o = out + ((size_t)b * NCH * K_NB + k) * M_CTR + m;
#pragma unroll
    for (int ch = 0; ch < NCH; ++ch)
        *(float2*)&o[(size_t)ch * CH_STRIDE] = make_float2(v0[ch], v1[ch]);
}

extern "C" void kernel_launch(void* const* d_in, const int* in_sizes, int n_in,
                              void* d_out, int out_size, void* d_ws, size_t ws_size,
                              hipStream_t stream) {
    const float* points  = (const float*)d_in[0];
    const float* centers = (const float*)d_in[1];
    const float* feats   = (const float*)d_in[2];
    float* out = (float*)d_out;

    char* ws = (char*)d_ws;
    int*    idx     = (int*)ws;                               // 1 MiB
    float*  pf      = (float*)(ws + (1u << 20));              // 4.5 MiB
    float4* cells   = (float4*)(ws + 6u * (1u << 20));        // 2 MiB
    int*    cellcnt = (int*)(ws + 9u * (1u << 20));           // 8 KB

    build_kernel<<<B_SZ + B_SZ * (N_PTS / 64), 1024, 0, stream>>>(
        points, feats, cells, cellcnt, pf);
    ball_query_kernel<<<(B_SZ * M_CTR) / 4, 256, 0, stream>>>(
        cells, cellcnt, centers, idx);
    gather_kernel<<<(B_SZ * K_NB * M_CTR / 2) / 256, 256, 0, stream>>>(
        pf, centers, idx, out);
}